// Round 23
// baseline (611.694 us; speedup 1.0000x reference)
//
#include <hip/hip_runtime.h>
#include <math.h>

#define N_ROWS 32768
#define D 256
#define K 1024
#define DEPTH 3
#define MARGIN 0.002f

typedef __bf16 bf16x8 __attribute__((ext_vector_type(8)));
typedef float f32x4 __attribute__((ext_vector_type(4)));
typedef __attribute__((ext_vector_type(8))) unsigned short u16x8;

// ---- ws layout (bytes) ----
// 0        idxAll[3][32768] int   -> 393216
// 393216   counts[3][1024] int    -> 405504  (zeroed by prep block 384)
// 405504   flags[32768] int       -> 536576  (0 none / -1 full / i2+1 pair)
// 536576   ssepart[3][2048] dbl   -> 585728
// 585728   e2f[3][1024] float     -> 598016 (pad 598080)
// 598080   cbp bf16 [3][1024][512]-> 3743808
// 3743808  res fp32 [32768][256]  -> 37298240

__device__ __forceinline__ void gload_lds16(const void* g, void* l) {
    __builtin_amdgcn_global_load_lds(
        (const __attribute__((address_space(1))) void*)g,
        (__attribute__((address_space(3))) void*)l, 16, 0, 0);
}

__device__ __forceinline__ unsigned short f2bf(float f) {
    unsigned u = __float_as_uint(f);
    return (unsigned short)((u + 0x7fffu + ((u >> 16) & 1u)) >> 16);
}

// blocks [0,384): cbs -> cbp + e2 ; block 384: zero counts
__global__ __launch_bounds__(256) void prep_kernel(
    const float* __restrict__ cbs, unsigned short* __restrict__ cbp,
    float* __restrict__ e2f, int* __restrict__ counts)
{
    if (blockIdx.x == 384) {
        for (int i = threadIdx.x; i < 3072; i += 256) counts[i] = 0;
        return;
    }
    int t = blockIdx.x * 256 + threadIdx.x;    // 98304 = 3072 rows * 32
    int row = t >> 5;
    int k8 = (t & 31) * 8;
    size_t off = (size_t)row * D + k8;
    float4 v0 = *(const float4*)(cbs + off);
    float4 v1 = *(const float4*)(cbs + off + 4);
    float v[8] = {v0.x, v0.y, v0.z, v0.w, v1.x, v1.y, v1.z, v1.w};
    u16x8 hv, lv;
    double s = 0.0;
    #pragma unroll
    for (int j = 0; j < 8; ++j) {
        unsigned short h = f2bf(v[j]);
        hv[j] = h;
        float hf = __uint_as_float(((unsigned)h) << 16);
        lv[j] = f2bf(v[j] - hf);
        s = fma((double)v[j], (double)v[j], s);
    }
    *(u16x8*)(cbp + (size_t)row * 512 + k8) = hv;
    *(u16x8*)(cbp + (size_t)row * 512 + 256 + k8) = lv;
    #pragma unroll
    for (int m = 1; m <= 16; m <<= 1) s += __shfl_xor(s, m, 32);
    if ((threadIdx.x & 31) == 0) e2f[row] = (float)s;
}

// R19-proven argmin + top-3 tracking (d3 value; i1,i2 packed in pi) +
// folded prev-stage refine: pair-exact (common) or full scan (d3-tie, rare).
__global__ __launch_bounds__(512, 2) void mfma_argmin_kernel(
    const unsigned short* __restrict__ cbp,   // [1024][512] packed bf16 (stage d)
    const float* __restrict__ in,             // fp32 residual-before-prev-update
    const float* __restrict__ e2f,            // [1024] (stage d)
    int* __restrict__ idxOut, int* flags,
    int* prevIdx, const float* __restrict__ prevCb,
    float* __restrict__ resOut, double* __restrict__ sseOut,
    int* __restrict__ prevCounts, int firstStage)
{
    __shared__ __align__(16) __bf16 Bsm[128 * 512];    // 128 KB resident rows
    __shared__ __align__(16) __bf16 Aw[8 * 2048];      // 32 KB (slices / scratch)

    const int tid = threadIdx.x;
    const int lane = tid & 63;
    const int w = tid >> 6;
    const int hi = lane >> 4;
    const int lo16 = lane & 15;
    const int row0 = blockIdx.x * 128;

    // ---- folded refine of PREVIOUS stage ----
    if (!firstStage) {
        char* scr = (char*)Aw;
        float4* rres = (float4*)scr;               // 1 KB
        double* bd   = (double*)(scr + 1024);      // 4 KB
        int*  bidxS  = (int*)(scr + 5120);         // 2 KB
        int*  list   = (int*)(scr + 7168);         // 32 ints
        int*  lflag  = (int*)(scr + 7296);         // 32 ints
        int*  nflag  = (int*)(scr + 7424);
        double* sred = (double*)(scr + 7432);      // 8 doubles
        if (tid == 0) *nflag = 0;
        __syncthreads();
        if (tid < 128) {
            int fl = flags[row0 + tid];
            if (fl != 0) {
                int pos = atomicAdd(nflag, 1);
                if (pos < 32) { list[pos] = row0 + tid; lflag[pos] = fl; }
            }
        }
        __syncthreads();
        int nf = *nflag; if (nf > 32) nf = 32;
        for (int f = 0; f < nf; ++f) {
            int row = list[f];
            int fl  = lflag[f];
            if (fl > 0) {
                // ---- pair-exact: cA = current best, cB = fl-1 ----
                int cA = prevIdx[row], cB = fl - 1;
                int code = (tid < 256) ? cA : cB;
                int dd = tid & 255;
                double a = (double)in[(size_t)row * D + dd]
                         - (double)prevCb[(size_t)code * D + dd];
                double s = a * a;
                #pragma unroll
                for (int o = 32; o > 0; o >>= 1) s += __shfl_down(s, o, 64);
                if (lane == 0) sred[w] = s;
                __syncthreads();
                if (tid == 0) {
                    double dA = (sred[0] + sred[1]) + (sred[2] + sred[3]);
                    double dB = (sred[4] + sred[5]) + (sred[6] + sred[7]);
                    prevIdx[row] = (dB < dA || (dB == dA && cB < cA)) ? cB : cA;
                }
                __syncthreads();
            } else {
                // ---- full exact scan (rare: d3 within margin) ----
                if (tid < 64)
                    rres[tid] = ((const float4*)(in + (size_t)row * D))[tid];
                __syncthreads();
                double best = 1e300; int bi = 0;
                for (int j = 0; j < 2; ++j) {
                    int c = tid * 2 + j;
                    const float4* cp = (const float4*)(prevCb + (size_t)c * D);
                    double s0 = 0.0, s1 = 0.0, s2 = 0.0, s3 = 0.0;
                    for (int k = 0; k < 16; ++k) {
                        float4 c0 = cp[k], c1 = cp[k + 16], c2 = cp[k + 32], c3 = cp[k + 48];
                        float4 r0 = rres[k], r1 = rres[k + 16], r2 = rres[k + 32], r3 = rres[k + 48];
                        double a;
                        a = (double)r0.x - (double)c0.x; s0 = fma(a, a, s0);
                        a = (double)r0.y - (double)c0.y; s0 = fma(a, a, s0);
                        a = (double)r0.z - (double)c0.z; s0 = fma(a, a, s0);
                        a = (double)r0.w - (double)c0.w; s0 = fma(a, a, s0);
                        a = (double)r1.x - (double)c1.x; s1 = fma(a, a, s1);
                        a = (double)r1.y - (double)c1.y; s1 = fma(a, a, s1);
                        a = (double)r1.z - (double)c1.z; s1 = fma(a, a, s1);
                        a = (double)r1.w - (double)c1.w; s1 = fma(a, a, s1);
                        a = (double)r2.x - (double)c2.x; s2 = fma(a, a, s2);
                        a = (double)r2.y - (double)c2.y; s2 = fma(a, a, s2);
                        a = (double)r2.z - (double)c2.z; s2 = fma(a, a, s2);
                        a = (double)r2.w - (double)c2.w; s2 = fma(a, a, s2);
                        a = (double)r3.x - (double)c3.x; s3 = fma(a, a, s3);
                        a = (double)r3.y - (double)c3.y; s3 = fma(a, a, s3);
                        a = (double)r3.z - (double)c3.z; s3 = fma(a, a, s3);
                        a = (double)r3.w - (double)c3.w; s3 = fma(a, a, s3);
                    }
                    double s = (s0 + s1) + (s2 + s3);
                    if (s < best || (s == best && c < bi)) { best = s; bi = c; }
                }
                bd[tid] = best; bidxS[tid] = bi;
                __syncthreads();
                for (int off = 256; off > 0; off >>= 1) {
                    if (tid < off) {
                        if (bd[tid + off] < bd[tid] ||
                            (bd[tid + off] == bd[tid] && bidxS[tid + off] < bidxS[tid])) {
                            bd[tid] = bd[tid + off]; bidxS[tid] = bidxS[tid + off];
                        }
                    }
                    __syncthreads();
                }
                if (tid == 0) prevIdx[row] = bidxS[0];
                __syncthreads();
            }
        }
        __syncthreads();   // refined prevIdx visible block-wide
    }

    int aPre[2];
    #pragma unroll
    for (int m = 0; m < 2; ++m) {
        int cl = m * 16 + lo16;
        aPre[m] = cl * 64 + ((hi ^ ((cl ^ (cl >> 2)) & 3)) * 16);
    }
    int bPre[8];
    #pragma unroll
    for (int n = 0; n < 8; ++n) {
        int rw = n * 16 + lo16;
        bPre[n] = (rw * 1024 + hi * 16) ^ ((rw & 7) << 4);
    }
    int aSrcOff[2], aDstOff[2];
    #pragma unroll
    for (int i = 0; i < 2; ++i) {
        int q = i * 64 + lane;
        int cL = q >> 2;
        int hh = (q & 3) ^ ((cL ^ (cL >> 2)) & 3);
        aSrcOff[i] = cL * 512 + hh * 8;
        aDstOff[i] = q * 16;
    }
    char* slice = (char*)Aw + w * 4096;
    const unsigned short* aWaveBase = cbp + (size_t)(w * 32) * 512;

    // ---- prologue: apply prev-stage update (optional) + pack -> swizzled Bsm ----
    double sacc = 0.0;
    #pragma unroll
    for (int p = 0; p < 8; ++p) {
        int idx = p * 512 + tid;
        int row = idx >> 5;
        int c = idx & 31;
        size_t goff = (size_t)(row0 + row) * 256 + c * 8;
        float4 v0 = *(const float4*)(in + goff);
        float4 v1 = *(const float4*)(in + goff + 4);
        if (!firstStage) {
            int ci = prevIdx[row0 + row];
            const float4* cb4 = (const float4*)(prevCb + (size_t)ci * 256 + c * 8);
            float4 c0 = cb4[0], c1 = cb4[1];
            v0.x -= c0.x; v0.y -= c0.y; v0.z -= c0.z; v0.w -= c0.w;
            v1.x -= c1.x; v1.y -= c1.y; v1.z -= c1.z; v1.w -= c1.w;
            *(float4*)(resOut + goff) = v0;
            *(float4*)(resOut + goff + 4) = v1;
            sacc = fma((double)v0.x, (double)v0.x, sacc);
            sacc = fma((double)v0.y, (double)v0.y, sacc);
            sacc = fma((double)v0.z, (double)v0.z, sacc);
            sacc = fma((double)v0.w, (double)v0.w, sacc);
            sacc = fma((double)v1.x, (double)v1.x, sacc);
            sacc = fma((double)v1.y, (double)v1.y, sacc);
            sacc = fma((double)v1.z, (double)v1.z, sacc);
            sacc = fma((double)v1.w, (double)v1.w, sacc);
        }
        float v[8] = {v0.x, v0.y, v0.z, v0.w, v1.x, v1.y, v1.z, v1.w};
        u16x8 hv, lv;
        #pragma unroll
        for (int j = 0; j < 8; ++j) {
            unsigned short h = f2bf(v[j]);
            hv[j] = h;
            float hf = __uint_as_float(((unsigned)h) << 16);
            lv[j] = f2bf(v[j] - hf);
        }
        const int sw = row & 7;
        *(u16x8*)((char*)Bsm + row * 1024 + ((c ^ sw) << 4)) = hv;
        *(u16x8*)((char*)Bsm + row * 1024 + (((32 + c) ^ sw) << 4)) = lv;
    }
    if (!firstStage) {
        #pragma unroll
        for (int o = 32; o > 0; o >>= 1) sacc += __shfl_down(sacc, o, 64);
        if (lane == 0) sseOut[blockIdx.x * 8 + w] = sacc;
        if (tid < 128) atomicAdd(prevCounts + prevIdx[row0 + tid], 1);
    }
    // issue first A window
    #pragma unroll
    for (int i = 0; i < 2; ++i)
        gload_lds16(aWaveBase + aSrcOff[i], slice + aDstOff[i]);

    float d1[8], d2[8], d3[8];
    int   pi[8];                 // (i1<<10) | i2
    #pragma unroll
    for (int n = 0; n < 8; ++n) {
        d1[n] = 3.4e38f; d2[n] = 3.4e38f; d3[n] = 3.4e38f;
        pi[n] = (1023 << 10) | 1023;
    }

    __syncthreads();   // Bsm pack visible

    #pragma unroll
    for (int pass = 0; pass < 2; ++pass) {
        const unsigned short* ccA = aWaveBase + (size_t)(2 * pass) * (256 * 512);
        const unsigned short* ccB = ccA + 256 * 512;
        f32x4 accP[2][8], accQ[2][8];
        #pragma unroll
        for (int m = 0; m < 2; ++m)
            #pragma unroll
            for (int n = 0; n < 8; ++n) {
                accP[m][n] = (f32x4){0.f, 0.f, 0.f, 0.f};
                accQ[m][n] = (f32x4){0.f, 0.f, 0.f, 0.f};
            }

        for (int jp = 0; jp < 8; ++jp) {
            const int ofH = jp * 32, ofL = 256 + jp * 32;
            const int kH = jp * 64, kL = 512 + jp * 64;

            #pragma unroll
            for (int i = 0; i < 2; ++i)
                gload_lds16(ccA + ofH + aSrcOff[i], slice + aDstOff[i]);
            #pragma unroll
            for (int i = 0; i < 2; ++i)
                gload_lds16(ccA + ofL + aSrcOff[i], slice + 2048 + aDstOff[i]);
            asm volatile("s_waitcnt vmcnt(0)" ::: "memory");

            bf16x8 Bh[8];
            #pragma unroll
            for (int n = 0; n < 8; ++n)
                Bh[n] = *(const bf16x8*)((const char*)Bsm + (bPre[n] ^ kH));

            {   // ccA
                bf16x8 Ah[2], Al[2];
                #pragma unroll
                for (int m = 0; m < 2; ++m) {
                    Ah[m] = *(const bf16x8*)(slice + aPre[m]);
                    Al[m] = *(const bf16x8*)(slice + 2048 + aPre[m]);
                }
                #pragma unroll
                for (int m = 0; m < 2; ++m)
                    #pragma unroll
                    for (int n = 0; n < 8; ++n)
                        accP[m][n] = __builtin_amdgcn_mfma_f32_16x16x32_bf16(
                            Ah[m], Bh[n], accP[m][n], 0, 0, 0);
                #pragma unroll
                for (int m = 0; m < 2; ++m)
                    #pragma unroll
                    for (int n = 0; n < 8; ++n)
                        accP[m][n] = __builtin_amdgcn_mfma_f32_16x16x32_bf16(
                            Al[m], Bh[n], accP[m][n], 0, 0, 0);
                #pragma unroll
                for (int n = 0; n < 8; ++n) {
                    bf16x8 blv = *(const bf16x8*)((const char*)Bsm + (bPre[n] ^ kL));
                    #pragma unroll
                    for (int m = 0; m < 2; ++m)
                        accP[m][n] = __builtin_amdgcn_mfma_f32_16x16x32_bf16(
                            Ah[m], blv, accP[m][n], 0, 0, 0);
                }
            }

            #pragma unroll
            for (int i = 0; i < 2; ++i)
                gload_lds16(ccB + ofH + aSrcOff[i], slice + aDstOff[i]);
            #pragma unroll
            for (int i = 0; i < 2; ++i)
                gload_lds16(ccB + ofL + aSrcOff[i], slice + 2048 + aDstOff[i]);
            asm volatile("s_waitcnt vmcnt(0)" ::: "memory");

            {   // ccB
                bf16x8 Ah[2], Al[2];
                #pragma unroll
                for (int m = 0; m < 2; ++m) {
                    Ah[m] = *(const bf16x8*)(slice + aPre[m]);
                    Al[m] = *(const bf16x8*)(slice + 2048 + aPre[m]);
                }
                #pragma unroll
                for (int m = 0; m < 2; ++m)
                    #pragma unroll
                    for (int n = 0; n < 8; ++n)
                        accQ[m][n] = __builtin_amdgcn_mfma_f32_16x16x32_bf16(
                            Ah[m], Bh[n], accQ[m][n], 0, 0, 0);
                #pragma unroll
                for (int m = 0; m < 2; ++m)
                    #pragma unroll
                    for (int n = 0; n < 8; ++n)
                        accQ[m][n] = __builtin_amdgcn_mfma_f32_16x16x32_bf16(
                            Al[m], Bh[n], accQ[m][n], 0, 0, 0);
                #pragma unroll
                for (int n = 0; n < 8; ++n) {
                    bf16x8 blv = *(const bf16x8*)((const char*)Bsm + (bPre[n] ^ kL));
                    #pragma unroll
                    for (int m = 0; m < 2; ++m)
                        accQ[m][n] = __builtin_amdgcn_mfma_f32_16x16x32_bf16(
                            Ah[m], blv, accQ[m][n], 0, 0, 0);
                }
            }
        }

        // ---- epilogues: top-3 update (codes ascending per lane) ----
        #pragma unroll
        for (int half = 0; half < 2; ++half) {
            const int cb0 = pass * 512 + half * 256 + w * 32;
            float e2a[2][4];
            #pragma unroll
            for (int m = 0; m < 2; ++m) {
                float4 t = *(const float4*)(e2f + cb0 + m * 16 + hi * 4);
                e2a[m][0] = t.x; e2a[m][1] = t.y; e2a[m][2] = t.z; e2a[m][3] = t.w;
            }
            #pragma unroll
            for (int n = 0; n < 8; ++n)
                #pragma unroll
                for (int m = 0; m < 2; ++m)
                    #pragma unroll
                    for (int r = 0; r < 4; ++r) {
                        float dv = e2a[m][r] - 2.0f *
                            (half == 0 ? accP[m][n][r] : accQ[m][n][r]);
                        int c = cb0 + m * 16 + hi * 4 + r;
                        bool lt1 = dv < d1[n];
                        bool lt2 = dv < d2[n];
                        bool lt3 = dv < d3[n];
                        d3[n] = lt2 ? d2[n] : (lt3 ? dv : d3[n]);
                        int p = pi[n];
                        pi[n] = lt1 ? ((c << 10) | (p >> 10))
                                    : (lt2 ? ((p & 0xFFC00) | c) : p);
                        d2[n] = lt1 ? d1[n] : (lt2 ? dv : d2[n]);
                        d1[n] = lt1 ? dv : d1[n];
                    }
        }
    }

    // butterfly merge across the 4 hi-groups (top-3)
    #pragma unroll
    for (int n = 0; n < 8; ++n) {
        #pragma unroll
        for (int mk = 0; mk < 2; ++mk) {
            int mask = mk ? 32 : 16;
            float od1 = __shfl_xor(d1[n], mask, 64);
            float od2 = __shfl_xor(d2[n], mask, 64);
            float od3 = __shfl_xor(d3[n], mask, 64);
            int   op  = __shfl_xor(pi[n], mask, 64);
            int ci1 = pi[n] >> 10, ci2 = pi[n] & 1023;
            int oi1 = op >> 10,    oi2 = op & 1023;
            // insert (od1, oi1)
            if (od1 < d1[n] || (od1 == d1[n] && oi1 < ci1)) {
                d3[n] = d2[n]; d2[n] = d1[n]; ci2 = ci1; d1[n] = od1; ci1 = oi1;
            } else if (od1 < d2[n] || (od1 == d2[n] && oi1 < ci2)) {
                d3[n] = d2[n]; d2[n] = od1; ci2 = oi1;
            } else if (od1 < d3[n]) d3[n] = od1;
            // insert (od2, oi2)
            if (od2 < d1[n] || (od2 == d1[n] && oi2 < ci1)) {
                d3[n] = d2[n]; d2[n] = d1[n]; ci2 = ci1; d1[n] = od2; ci1 = oi2;
            } else if (od2 < d2[n] || (od2 == d2[n] && oi2 < ci2)) {
                d3[n] = d2[n]; d2[n] = od2; ci2 = oi2;
            } else if (od2 < d3[n]) d3[n] = od2;
            d3[n] = fminf(d3[n], od3);
            pi[n] = (ci1 << 10) | ci2;
        }
    }

    // cross-wave merge via LDS scratch (Aw dead)
    __syncthreads();
    float4* mb = (float4*)Aw;      // 8*128 float4 = 16 KB
    if (lane < 16) {
        #pragma unroll
        for (int n = 0; n < 8; ++n)
            mb[w * 128 + n * 16 + lo16] =
                make_float4(d1[n], d2[n], d3[n], __int_as_float(pi[n]));
    }
    __syncthreads();
    if (tid < 128) {
        float fd1 = 3.4e38f, fd2 = 3.4e38f, fd3 = 3.4e38f;
        int fc1 = 1023, fc2 = 1023;
        #pragma unroll
        for (int pc = 0; pc < 8; ++pc) {
            float4 p = mb[pc * 128 + tid];
            float pd1 = p.x, pd2 = p.y, pd3 = p.z;
            int pp = __float_as_int(p.w);
            int pc1 = pp >> 10, pc2 = pp & 1023;
            if (pd1 < fd1 || (pd1 == fd1 && pc1 < fc1)) {
                fd3 = fd2; fd2 = fd1; fc2 = fc1; fd1 = pd1; fc1 = pc1;
            } else if (pd1 < fd2 || (pd1 == fd2 && pc1 < fc2)) {
                fd3 = fd2; fd2 = pd1; fc2 = pc1;
            } else if (pd1 < fd3) fd3 = pd1;
            if (pd2 < fd1 || (pd2 == fd1 && pc2 < fc1)) {
                fd3 = fd2; fd2 = fd1; fc2 = fc1; fd1 = pd2; fc1 = pc2;
            } else if (pd2 < fd2 || (pd2 == fd2 && pc2 < fc2)) {
                fd3 = fd2; fd2 = pd2; fc2 = pc2;
            } else if (pd2 < fd3) fd3 = pd2;
            fd3 = fminf(fd3, pd3);
        }
        int row = row0 + tid;
        idxOut[row] = fc1;
        int fl = 0;
        if (fd2 - fd1 < MARGIN) fl = (fd3 - fd1 < MARGIN) ? -1 : (fc2 + 1);
        flags[row] = fl;
    }
}

// last-stage: folded refine (pair-exact or full) + compose + update.
__global__ __launch_bounds__(256) void update_kernel(
    const float* __restrict__ in, const float* __restrict__ z,
    float* __restrict__ qtotOut,
    const float* __restrict__ cbD, int* idxStage,
    const int* __restrict__ flags, const int* __restrict__ idxAll,
    float* __restrict__ comp,
    int* __restrict__ counts, double* __restrict__ ssepart)
{
    __shared__ float4 rres[64];
    __shared__ double bd[256];
    __shared__ int    bidxS[256];
    __shared__ int    list[16];
    __shared__ int    lflag[16];
    __shared__ int    nflag;
    __shared__ double wsum[4];
    const int tid = threadIdx.x;

    // ---- folded refine: this block's 16 rows ----
    if (tid == 0) nflag = 0;
    __syncthreads();
    if (tid < 16) {
        int row = (tid >> 2) * 8192 + blockIdx.x * 4 + (tid & 3);
        int fl = flags[row];
        if (fl != 0) { int pos = atomicAdd(&nflag, 1); list[pos] = row; lflag[pos] = fl; }
    }
    __syncthreads();
    const int nf = nflag;
    for (int f = 0; f < nf; ++f) {
        int row = list[f];
        int fl  = lflag[f];
        if (fl > 0) {
            int cA = idxStage[row], cB = fl - 1;
            int code = (tid < 128) ? cA : cB;
            int d0 = (tid & 127) * 2;
            double a0 = (double)in[(size_t)row * D + d0]
                      - (double)cbD[(size_t)code * D + d0];
            double a1 = (double)in[(size_t)row * D + d0 + 1]
                      - (double)cbD[(size_t)code * D + d0 + 1];
            double s = a0 * a0 + a1 * a1;
            #pragma unroll
            for (int o = 32; o > 0; o >>= 1) s += __shfl_down(s, o, 64);
            int lane = tid & 63, wv = tid >> 6;
            if (lane == 0) wsum[wv] = s;
            __syncthreads();
            if (tid == 0) {
                double dA = wsum[0] + wsum[1];
                double dB = wsum[2] + wsum[3];
                idxStage[row] = (dB < dA || (dB == dA && cB < cA)) ? cB : cA;
            }
            __syncthreads();
        } else {
            if (tid < 64)
                rres[tid] = ((const float4*)(in + (size_t)row * D))[tid];
            __syncthreads();
            double best = 1e300; int bi = 0;
            for (int j = 0; j < 4; ++j) {
                int c = tid * 4 + j;
                const float4* cp = (const float4*)(cbD + (size_t)c * D);
                double s0 = 0.0, s1 = 0.0, s2 = 0.0, s3 = 0.0;
                for (int k = 0; k < 16; ++k) {
                    float4 c0 = cp[k], c1 = cp[k + 16], c2 = cp[k + 32], c3 = cp[k + 48];
                    float4 r0 = rres[k], r1 = rres[k + 16], r2 = rres[k + 32], r3 = rres[k + 48];
                    double a;
                    a = (double)r0.x - (double)c0.x; s0 = fma(a, a, s0);
                    a = (double)r0.y - (double)c0.y; s0 = fma(a, a, s0);
                    a = (double)r0.z - (double)c0.z; s0 = fma(a, a, s0);
                    a = (double)r0.w - (double)c0.w; s0 = fma(a, a, s0);
                    a = (double)r1.x - (double)c1.x; s1 = fma(a, a, s1);
                    a = (double)r1.y - (double)c1.y; s1 = fma(a, a, s1);
                    a = (double)r1.z - (double)c1.z; s1 = fma(a, a, s1);
                    a = (double)r1.w - (double)c1.w; s1 = fma(a, a, s1);
                    a = (double)r2.x - (double)c2.x; s2 = fma(a, a, s2);
                    a = (double)r2.y - (double)c2.y; s2 = fma(a, a, s2);
                    a = (double)r2.z - (double)c2.z; s2 = fma(a, a, s2);
                    a = (double)r2.w - (double)c2.w; s2 = fma(a, a, s2);
                    a = (double)r3.x - (double)c3.x; s3 = fma(a, a, s3);
                    a = (double)r3.y - (double)c3.y; s3 = fma(a, a, s3);
                    a = (double)r3.z - (double)c3.z; s3 = fma(a, a, s3);
                    a = (double)r3.w - (double)c3.w; s3 = fma(a, a, s3);
                }
                double s = (s0 + s1) + (s2 + s3);
                if (s < best || (s == best && c < bi)) { best = s; bi = c; }
            }
            bd[tid] = best; bidxS[tid] = bi;
            __syncthreads();
            for (int off = 128; off > 0; off >>= 1) {
                if (tid < off) {
                    if (bd[tid + off] < bd[tid] ||
                        (bd[tid + off] == bd[tid] && bidxS[tid + off] < bidxS[tid])) {
                        bd[tid] = bd[tid + off]; bidxS[tid] = bidxS[tid + off];
                    }
                }
                __syncthreads();
            }
            if (tid == 0) idxStage[row] = bidxS[0];
            __syncthreads();
        }
    }
    __syncthreads();   // refined idx visible block-wide

    // ---- compose for this block's 16 rows (stage-2 idx now final) ----
    if (tid < 16) {
        int row = (tid >> 2) * 8192 + blockIdx.x * 4 + (tid & 3);
        int v = idxAll[row] + (idxAll[N_ROWS + row] << 10)
              + (idxStage[row] << 20);
        comp[row] = (float)v;
    }

    // ---- streaming update ----
    double s = 0.0;
    const int base = blockIdx.x * 256 + tid;
    #pragma unroll
    for (int it = 0; it < 4; ++it) {
        int t = base + it * 524288;
        int row = t >> 6;
        int c4  = (t & 63) << 2;
        int idx = idxStage[row];
        size_t off = (size_t)row * D + c4;
        float4 iv = *(const float4*)(in + off);
        float4 cv = *(const float4*)(cbD + (size_t)idx * D + c4);
        float4 r;
        r.x = iv.x - cv.x; r.y = iv.y - cv.y;
        r.z = iv.z - cv.z; r.w = iv.w - cv.w;
        float4 zv = *(const float4*)(z + off);
        float4 q;
        q.x = zv.x - r.x; q.y = zv.y - r.y;
        q.z = zv.z - r.z; q.w = zv.w - r.w;
        *(float4*)(qtotOut + off) = q;
        s = fma((double)r.x, (double)r.x, s);
        s = fma((double)r.y, (double)r.y, s);
        s = fma((double)r.z, (double)r.z, s);
        s = fma((double)r.w, (double)r.w, s);
        if ((t & 63) == 0) atomicAdd(counts + idx, 1);
    }
    for (int o = 32; o > 0; o >>= 1) s += __shfl_down(s, o, 64);
    int lane = tid & 63, wv = tid >> 6;
    if (lane == 0) wsum[wv] = s;
    __syncthreads();
    if (tid == 0)
        ssepart[blockIdx.x] = wsum[0] + wsum[1] + wsum[2] + wsum[3];
}

// perplexity + loss only (compose moved into update)
__global__ void final_kernel(const int* __restrict__ counts,
                             const double* __restrict__ ssepart,
                             float* __restrict__ loss, float* __restrict__ perps)
{
    __shared__ double red[16];
    __shared__ double lossAcc;
    const int tid = threadIdx.x;   // 1024 threads
    if (tid == 0) lossAcc = 0.0;
    __syncthreads();
    for (int d = 0; d < DEPTH; ++d) {
        double p = (double)counts[d * K + tid] / 32768.0;
        double s = p * log(p + 1e-10);
        double q = ssepart[d * 2048 + tid] + ssepart[d * 2048 + 1024 + tid];
        for (int o = 32; o > 0; o >>= 1) {
            s += __shfl_down(s, o, 64);
            q += __shfl_down(q, o, 64);
        }
        if ((tid & 63) == 0) red[tid >> 6] = s;
        __syncthreads();
        if (tid == 0) {
            double tot = 0.0;
            for (int i = 0; i < 16; ++i) tot += red[i];
            perps[d] = (float)exp(-tot);
        }
        __syncthreads();
        if ((tid & 63) == 0) red[tid >> 6] = q;
        __syncthreads();
        if (tid == 0) {
            double tq = 0.0;
            for (int i = 0; i < 16; ++i) tq += red[i];
            lossAcc += tq;
        }
        __syncthreads();
    }
    if (tid == 0)
        loss[0] = (float)(1.25 * lossAcc / 8388608.0);
}

extern "C" void kernel_launch(void* const* d_in, const int* in_sizes, int n_in,
                              void* d_out, int out_size, void* d_ws, size_t ws_size,
                              hipStream_t stream)
{
    const float* z   = (const float*)d_in[0];
    const float* cbs = (const float*)d_in[1];
    float* out = (float*)d_out;
    char*  ws  = (char*)d_ws;

    int*            idxAll   = (int*)ws;
    int*            counts   = (int*)(ws + 393216);
    int*            flags    = (int*)(ws + 405504);
    double*         ssepart  = (double*)(ws + 536576);
    float*          e2f      = (float*)(ws + 585728);
    unsigned short* cbp      = (unsigned short*)(ws + 598080);
    float*          res      = (float*)(ws + 3743808);

    float* qtot  = out;                       // 8388608 elems
    float* loss  = out + 8388608;             // 1
    float* comp  = out + 8388609;             // 32768
    float* perps = out + 8388609 + 32768;     // 3

    prep_kernel<<<385, 256, 0, stream>>>(cbs, cbp, e2f, counts);

    for (int d = 0; d < DEPTH; ++d) {
        const float* in = (d <= 1) ? z : res;
        int*         pIdx = (d == 0) ? idxAll : idxAll + (d - 1) * N_ROWS;
        const float* pCb  = (d == 0) ? cbs : cbs + (size_t)(d - 1) * K * D;
        mfma_argmin_kernel<<<256, 512, 0, stream>>>(
            cbp + (size_t)d * K * 512, in, e2f + d * K,
            idxAll + d * N_ROWS, flags,
            pIdx, pCb, res, ssepart + (size_t)(d - 1) * 2048,
            counts + (d - 1) * K, (d == 0) ? 1 : 0);
    }

    update_kernel<<<2048, 256, 0, stream>>>(
        res, z, qtot, cbs + (size_t)2 * K * D, idxAll + 2 * N_ROWS,
        flags, idxAll, comp, counts + 2 * K, ssepart + 2 * 2048);

    final_kernel<<<1, 1024, 0, stream>>>(counts, ssepart, loss, perps);
}

// Round 25
// 364.927 us; speedup vs baseline: 1.6762x; 1.6762x over previous
//
#include <hip/hip_runtime.h>
#include <math.h>

#define N_ROWS 32768
#define D 256
#define K 1024
#define DEPTH 3
#define MARGIN 0.002f

typedef __bf16 bf16x8 __attribute__((ext_vector_type(8)));
typedef float f32x4 __attribute__((ext_vector_type(4)));
typedef __attribute__((ext_vector_type(8))) unsigned short u16x8;

// ---- ws layout (bytes) ----
// 0        idxAll[3][32768] int   -> 393216
// 393216   counts[3][1024] int    -> 405504  (zeroed by prep block 384)
// 405504   flags[32768] int       -> 536576
// 536576   ssepart[3][2048] dbl   -> 585728
// 585728   e2f[3][1024] float     -> 598016 (pad 598080)
// 598080   cbp bf16 [3][1024][512]-> 3743808
// 3743808  res fp32 [32768][256]  -> 37298240

__device__ __forceinline__ void gload_lds16(const void* g, void* l) {
    __builtin_amdgcn_global_load_lds(
        (const __attribute__((address_space(1))) void*)g,
        (__attribute__((address_space(3))) void*)l, 16, 0, 0);
}

__device__ __forceinline__ unsigned short f2bf(float f) {
    unsigned u = __float_as_uint(f);
    return (unsigned short)((u + 0x7fffu + ((u >> 16) & 1u)) >> 16);
}

// blocks [0,384): cbs -> cbp + e2 ; block 384: zero counts
__global__ __launch_bounds__(256) void prep_kernel(
    const float* __restrict__ cbs, unsigned short* __restrict__ cbp,
    float* __restrict__ e2f, int* __restrict__ counts)
{
    if (blockIdx.x == 384) {
        for (int i = threadIdx.x; i < 3072; i += 256) counts[i] = 0;
        return;
    }
    int t = blockIdx.x * 256 + threadIdx.x;    // 98304 = 3072 rows * 32
    int row = t >> 5;
    int k8 = (t & 31) * 8;
    size_t off = (size_t)row * D + k8;
    float4 v0 = *(const float4*)(cbs + off);
    float4 v1 = *(const float4*)(cbs + off + 4);
    float v[8] = {v0.x, v0.y, v0.z, v0.w, v1.x, v1.y, v1.z, v1.w};
    u16x8 hv, lv;
    double s = 0.0;
    #pragma unroll
    for (int j = 0; j < 8; ++j) {
        unsigned short h = f2bf(v[j]);
        hv[j] = h;
        float hf = __uint_as_float(((unsigned)h) << 16);
        lv[j] = f2bf(v[j] - hf);
        s = fma((double)v[j], (double)v[j], s);
    }
    *(u16x8*)(cbp + (size_t)row * 512 + k8) = hv;
    *(u16x8*)(cbp + (size_t)row * 512 + 256 + k8) = lv;
    #pragma unroll
    for (int m = 1; m <= 16; m <<= 1) s += __shfl_xor(s, m, 32);
    if ((threadIdx.x & 31) == 0) e2f[row] = (float)s;
}

// R19-proven argmin + folded prev-stage refine pre-phase. Order per block:
// refine(prev) -> barrier -> fused prev-update prologue -> MFMA -> merge.
__global__ __launch_bounds__(512, 2) void mfma_argmin_kernel(
    const unsigned short* __restrict__ cbp,   // [1024][512] packed bf16 (stage d)
    const float* __restrict__ in,             // fp32 residual-before-prev-update
    const float* __restrict__ e2f,            // [1024] (stage d)
    int* __restrict__ idxOut, int* flags,
    int* prevIdx, const float* __restrict__ prevCb,
    float* __restrict__ resOut, double* __restrict__ sseOut,
    int* __restrict__ prevCounts, int firstStage)
{
    __shared__ __align__(16) __bf16 Bsm[128 * 512];    // 128 KB resident rows
    __shared__ __align__(16) __bf16 Aw[8 * 2048];      // 32 KB (slices / scratch)

    const int tid = threadIdx.x;
    const int lane = tid & 63;
    const int w = tid >> 6;            // wave owns codes [w*32, w*32+32) of each cc
    const int hi = lane >> 4;
    const int lo16 = lane & 15;
    const int row0 = blockIdx.x * 128;

    // ---- folded refine of PREVIOUS stage (rare rows) ----
    if (!firstStage) {
        char* scr = (char*)Aw;
        float4* rres = (float4*)scr;               // 1 KB
        double* bd   = (double*)(scr + 1024);      // 4 KB
        int*  bidxS  = (int*)(scr + 5120);         // 2 KB
        int*  list   = (int*)(scr + 7168);         // 512 B
        int*  nflag  = (int*)(scr + 7680);
        if (tid == 0) *nflag = 0;
        __syncthreads();
        if (tid < 128 && flags[row0 + tid]) {
            int pos = atomicAdd(nflag, 1);
            list[pos] = row0 + tid;
        }
        __syncthreads();
        const int nf = *nflag;
        for (int f = 0; f < nf; ++f) {
            int row = list[f];
            if (tid < 64)
                rres[tid] = ((const float4*)(in + (size_t)row * D))[tid];
            __syncthreads();
            double best = 1e300; int bi = 0;
            for (int j = 0; j < 2; ++j) {
                int c = tid * 2 + j;
                const float4* cp = (const float4*)(prevCb + (size_t)c * D);
                double s0 = 0.0, s1 = 0.0, s2 = 0.0, s3 = 0.0;
                for (int k = 0; k < 16; ++k) {
                    float4 c0 = cp[k], c1 = cp[k + 16], c2 = cp[k + 32], c3 = cp[k + 48];
                    float4 r0 = rres[k], r1 = rres[k + 16], r2 = rres[k + 32], r3 = rres[k + 48];
                    double a;
                    a = (double)r0.x - (double)c0.x; s0 = fma(a, a, s0);
                    a = (double)r0.y - (double)c0.y; s0 = fma(a, a, s0);
                    a = (double)r0.z - (double)c0.z; s0 = fma(a, a, s0);
                    a = (double)r0.w - (double)c0.w; s0 = fma(a, a, s0);
                    a = (double)r1.x - (double)c1.x; s1 = fma(a, a, s1);
                    a = (double)r1.y - (double)c1.y; s1 = fma(a, a, s1);
                    a = (double)r1.z - (double)c1.z; s1 = fma(a, a, s1);
                    a = (double)r1.w - (double)c1.w; s1 = fma(a, a, s1);
                    a = (double)r2.x - (double)c2.x; s2 = fma(a, a, s2);
                    a = (double)r2.y - (double)c2.y; s2 = fma(a, a, s2);
                    a = (double)r2.z - (double)c2.z; s2 = fma(a, a, s2);
                    a = (double)r2.w - (double)c2.w; s2 = fma(a, a, s2);
                    a = (double)r3.x - (double)c3.x; s3 = fma(a, a, s3);
                    a = (double)r3.y - (double)c3.y; s3 = fma(a, a, s3);
                    a = (double)r3.z - (double)c3.z; s3 = fma(a, a, s3);
                    a = (double)r3.w - (double)c3.w; s3 = fma(a, a, s3);
                }
                double s = (s0 + s1) + (s2 + s3);
                if (s < best || (s == best && c < bi)) { best = s; bi = c; }
            }
            bd[tid] = best; bidxS[tid] = bi;
            __syncthreads();
            for (int off = 256; off > 0; off >>= 1) {
                if (tid < off) {
                    if (bd[tid + off] < bd[tid] ||
                        (bd[tid + off] == bd[tid] && bidxS[tid + off] < bidxS[tid])) {
                        bd[tid] = bd[tid + off]; bidxS[tid] = bidxS[tid + off];
                    }
                }
                __syncthreads();
            }
            if (tid == 0) prevIdx[row] = bidxS[0];
            __syncthreads();
        }
        __syncthreads();   // refined prevIdx visible block-wide
    }

    int aPre[2];                       // frag offsets within a 2KB window
    #pragma unroll
    for (int m = 0; m < 2; ++m) {
        int cl = m * 16 + lo16;
        aPre[m] = cl * 64 + ((hi ^ ((cl ^ (cl >> 2)) & 3)) * 16);
    }
    int bPre[8];
    #pragma unroll
    for (int n = 0; n < 8; ++n) {
        int rw = n * 16 + lo16;
        bPre[n] = (rw * 1024 + hi * 16) ^ ((rw & 7) << 4);
    }
    int aSrcOff[2], aDstOff[2];
    #pragma unroll
    for (int i = 0; i < 2; ++i) {
        int q = i * 64 + lane;
        int cL = q >> 2;
        int hh = (q & 3) ^ ((cL ^ (cL >> 2)) & 3);
        aSrcOff[i] = cL * 512 + hh * 8;
        aDstOff[i] = q * 16;
    }
    char* slice = (char*)Aw + w * 4096;
    const unsigned short* aWaveBase = cbp + (size_t)(w * 32) * 512;

    // ---- prologue: apply prev-stage update (optional) + pack -> swizzled Bsm ----
    double sacc = 0.0;
    #pragma unroll
    for (int p = 0; p < 8; ++p) {
        int idx = p * 512 + tid;
        int row = idx >> 5;
        int c = idx & 31;
        size_t goff = (size_t)(row0 + row) * 256 + c * 8;
        float4 v0 = *(const float4*)(in + goff);
        float4 v1 = *(const float4*)(in + goff + 4);
        if (!firstStage) {
            int ci = prevIdx[row0 + row];
            const float4* cb4 = (const float4*)(prevCb + (size_t)ci * 256 + c * 8);
            float4 c0 = cb4[0], c1 = cb4[1];
            v0.x -= c0.x; v0.y -= c0.y; v0.z -= c0.z; v0.w -= c0.w;
            v1.x -= c1.x; v1.y -= c1.y; v1.z -= c1.z; v1.w -= c1.w;
            *(float4*)(resOut + goff) = v0;
            *(float4*)(resOut + goff + 4) = v1;
            sacc = fma((double)v0.x, (double)v0.x, sacc);
            sacc = fma((double)v0.y, (double)v0.y, sacc);
            sacc = fma((double)v0.z, (double)v0.z, sacc);
            sacc = fma((double)v0.w, (double)v0.w, sacc);
            sacc = fma((double)v1.x, (double)v1.x, sacc);
            sacc = fma((double)v1.y, (double)v1.y, sacc);
            sacc = fma((double)v1.z, (double)v1.z, sacc);
            sacc = fma((double)v1.w, (double)v1.w, sacc);
        }
        float v[8] = {v0.x, v0.y, v0.z, v0.w, v1.x, v1.y, v1.z, v1.w};
        u16x8 hv, lv;
        #pragma unroll
        for (int j = 0; j < 8; ++j) {
            unsigned short h = f2bf(v[j]);
            hv[j] = h;
            float hf = __uint_as_float(((unsigned)h) << 16);
            lv[j] = f2bf(v[j] - hf);
        }
        const int sw = row & 7;
        *(u16x8*)((char*)Bsm + row * 1024 + ((c ^ sw) << 4)) = hv;
        *(u16x8*)((char*)Bsm + row * 1024 + (((32 + c) ^ sw) << 4)) = lv;
    }
    if (!firstStage) {
        #pragma unroll
        for (int o = 32; o > 0; o >>= 1) sacc += __shfl_down(sacc, o, 64);
        if (lane == 0) sseOut[blockIdx.x * 8 + w] = sacc;
        if (tid < 128) atomicAdd(prevCounts + prevIdx[row0 + tid], 1);
    }
    // issue first A window (slices are wave-private)
    #pragma unroll
    for (int i = 0; i < 2; ++i)
        gload_lds16(aWaveBase + aSrcOff[i], slice + aDstOff[i]);

    float d1[8], d2[8];
    int   i1[8], i2[8];
    #pragma unroll
    for (int n = 0; n < 8; ++n) {
        d1[n] = 3.4e38f; d2[n] = 3.4e38f;
        i1[n] = 0x7fffffff; i2[n] = 0x7fffffff;
    }

    __syncthreads();   // Bsm pack visible — only barrier before the merge

    #pragma unroll
    for (int pass = 0; pass < 2; ++pass) {
        const unsigned short* ccA = aWaveBase + (size_t)(2 * pass) * (256 * 512);
        const unsigned short* ccB = ccA + 256 * 512;
        f32x4 accP[2][8], accQ[2][8];
        #pragma unroll
        for (int m = 0; m < 2; ++m)
            #pragma unroll
            for (int n = 0; n < 8; ++n) {
                accP[m][n] = (f32x4){0.f, 0.f, 0.f, 0.f};
                accQ[m][n] = (f32x4){0.f, 0.f, 0.f, 0.f};
            }

        for (int jp = 0; jp < 8; ++jp) {
            const int ofH = jp * 32, ofL = 256 + jp * 32;
            const int kH = jp * 64, kL = 512 + jp * 64;

            // ---- stage ccA {hi,lo} windows into wave slice ----
            #pragma unroll
            for (int i = 0; i < 2; ++i)
                gload_lds16(ccA + ofH + aSrcOff[i], slice + aDstOff[i]);
            #pragma unroll
            for (int i = 0; i < 2; ++i)
                gload_lds16(ccA + ofL + aSrcOff[i], slice + 2048 + aDstOff[i]);
            asm volatile("s_waitcnt vmcnt(0)" ::: "memory");

            // ---- Bh frags (used 4x this jp) -> registers ----
            bf16x8 Bh[8];
            #pragma unroll
            for (int n = 0; n < 8; ++n)
                Bh[n] = *(const bf16x8*)((const char*)Bsm + (bPre[n] ^ kH));

            {   // ccA: Ah*Bh + Al*Bh + Ah*Bl (Bl read from LDS per use)
                bf16x8 Ah[2], Al[2];
                #pragma unroll
                for (int m = 0; m < 2; ++m) {
                    Ah[m] = *(const bf16x8*)(slice + aPre[m]);
                    Al[m] = *(const bf16x8*)(slice + 2048 + aPre[m]);
                }
                #pragma unroll
                for (int m = 0; m < 2; ++m)
                    #pragma unroll
                    for (int n = 0; n < 8; ++n)
                        accP[m][n] = __builtin_amdgcn_mfma_f32_16x16x32_bf16(
                            Ah[m], Bh[n], accP[m][n], 0, 0, 0);
                #pragma unroll
                for (int m = 0; m < 2; ++m)
                    #pragma unroll
                    for (int n = 0; n < 8; ++n)
                        accP[m][n] = __builtin_amdgcn_mfma_f32_16x16x32_bf16(
                            Al[m], Bh[n], accP[m][n], 0, 0, 0);
                #pragma unroll
                for (int n = 0; n < 8; ++n) {
                    bf16x8 blv = *(const bf16x8*)((const char*)Bsm + (bPre[n] ^ kL));
                    #pragma unroll
                    for (int m = 0; m < 2; ++m)
                        accP[m][n] = __builtin_amdgcn_mfma_f32_16x16x32_bf16(
                            Ah[m], blv, accP[m][n], 0, 0, 0);
                }
            }

            // ---- stage ccB {hi,lo} windows (same wave-private slice) ----
            #pragma unroll
            for (int i = 0; i < 2; ++i)
                gload_lds16(ccB + ofH + aSrcOff[i], slice + aDstOff[i]);
            #pragma unroll
            for (int i = 0; i < 2; ++i)
                gload_lds16(ccB + ofL + aSrcOff[i], slice + 2048 + aDstOff[i]);
            asm volatile("s_waitcnt vmcnt(0)" ::: "memory");

            {   // ccB: Bh still in registers; Bl from LDS per use
                bf16x8 Ah[2], Al[2];
                #pragma unroll
                for (int m = 0; m < 2; ++m) {
                    Ah[m] = *(const bf16x8*)(slice + aPre[m]);
                    Al[m] = *(const bf16x8*)(slice + 2048 + aPre[m]);
                }
                #pragma unroll
                for (int m = 0; m < 2; ++m)
                    #pragma unroll
                    for (int n = 0; n < 8; ++n)
                        accQ[m][n] = __builtin_amdgcn_mfma_f32_16x16x32_bf16(
                            Ah[m], Bh[n], accQ[m][n], 0, 0, 0);
                #pragma unroll
                for (int m = 0; m < 2; ++m)
                    #pragma unroll
                    for (int n = 0; n < 8; ++n)
                        accQ[m][n] = __builtin_amdgcn_mfma_f32_16x16x32_bf16(
                            Al[m], Bh[n], accQ[m][n], 0, 0, 0);
                #pragma unroll
                for (int n = 0; n < 8; ++n) {
                    bf16x8 blv = *(const bf16x8*)((const char*)Bsm + (bPre[n] ^ kL));
                    #pragma unroll
                    for (int m = 0; m < 2; ++m)
                        accQ[m][n] = __builtin_amdgcn_mfma_f32_16x16x32_bf16(
                            Ah[m], blv, accQ[m][n], 0, 0, 0);
                }
            }
        }

        // ---- epilogue ccA (accP) ----
        {
            const int cb0 = pass * 512 + w * 32;
            float e2a[2][4];
            #pragma unroll
            for (int m = 0; m < 2; ++m) {
                float4 t = *(const float4*)(e2f + cb0 + m * 16 + hi * 4);
                e2a[m][0] = t.x; e2a[m][1] = t.y; e2a[m][2] = t.z; e2a[m][3] = t.w;
            }
            #pragma unroll
            for (int n = 0; n < 8; ++n)
                #pragma unroll
                for (int m = 0; m < 2; ++m)
                    #pragma unroll
                    for (int r = 0; r < 4; ++r) {
                        float dv = e2a[m][r] - 2.0f * accP[m][n][r];
                        int c = cb0 + m * 16 + hi * 4 + r;
                        bool lt1 = dv < d1[n];
                        bool lt2 = dv < d2[n];
                        i2[n] = lt1 ? i1[n] : (lt2 ? c : i2[n]);
                        i1[n] = lt1 ? c : i1[n];
                        d2[n] = fminf(fmaxf(d1[n], dv), d2[n]);
                        d1[n] = fminf(d1[n], dv);
                    }
        }
        // ---- epilogue ccB (accQ) ----
        {
            const int cb0 = pass * 512 + 256 + w * 32;
            float e2a[2][4];
            #pragma unroll
            for (int m = 0; m < 2; ++m) {
                float4 t = *(const float4*)(e2f + cb0 + m * 16 + hi * 4);
                e2a[m][0] = t.x; e2a[m][1] = t.y; e2a[m][2] = t.z; e2a[m][3] = t.w;
            }
            #pragma unroll
            for (int n = 0; n < 8; ++n)
                #pragma unroll
                for (int m = 0; m < 2; ++m)
                    #pragma unroll
                    for (int r = 0; r < 4; ++r) {
                        float dv = e2a[m][r] - 2.0f * accQ[m][n][r];
                        int c = cb0 + m * 16 + hi * 4 + r;
                        bool lt1 = dv < d1[n];
                        bool lt2 = dv < d2[n];
                        i2[n] = lt1 ? i1[n] : (lt2 ? c : i2[n]);
                        i1[n] = lt1 ? c : i1[n];
                        d2[n] = fminf(fmaxf(d1[n], dv), d2[n]);
                        d1[n] = fminf(d1[n], dv);
                    }
        }
    }

    // butterfly merge across the 4 hi-groups
    #pragma unroll
    for (int n = 0; n < 8; ++n) {
        #pragma unroll
        for (int mk = 0; mk < 2; ++mk) {
            int mask = mk ? 32 : 16;
            float od1 = __shfl_xor(d1[n], mask, 64);
            float od2 = __shfl_xor(d2[n], mask, 64);
            int   oi1 = __shfl_xor(i1[n], mask, 64);
            int   oi2 = __shfl_xor(i2[n], mask, 64);
            if (od1 < d1[n] || (od1 == d1[n] && oi1 < i1[n])) { d2[n] = d1[n]; i2[n] = i1[n]; d1[n] = od1; i1[n] = oi1; }
            else if (od1 < d2[n] || (od1 == d2[n] && oi1 < i2[n])) { d2[n] = od1; i2[n] = oi1; }
            if (od2 < d1[n] || (od2 == d1[n] && oi2 < i1[n])) { d2[n] = d1[n]; i2[n] = i1[n]; d1[n] = od2; i1[n] = oi2; }
            else if (od2 < d2[n] || (od2 == d2[n] && oi2 < i2[n])) { d2[n] = od2; i2[n] = oi2; }
        }
    }

    // cross-wave merge via LDS scratch (Aw dead)
    __syncthreads();
    float4* mb = (float4*)Aw;      // 8*128 float4 = 16 KB (fits 32 KB Aw)
    if (lane < 16) {
        #pragma unroll
        for (int n = 0; n < 8; ++n)
            mb[w * 128 + n * 16 + lo16] =
                make_float4(d1[n], d2[n], __int_as_float(i1[n]), __int_as_float(i2[n]));
    }
    __syncthreads();
    if (tid < 128) {
        float fd1 = 3.4e38f, fd2 = 3.4e38f;
        int   fi1 = 0x7fffffff, fi2 = 0x7fffffff;
        #pragma unroll
        for (int pc = 0; pc < 8; ++pc) {
            float4 p = mb[pc * 128 + tid];
            float pd1 = p.x, pd2 = p.y;
            int   pi1 = __float_as_int(p.z), pi2 = __float_as_int(p.w);
            if (pd1 < fd1 || (pd1 == fd1 && pi1 < fi1)) { fd2 = fd1; fi2 = fi1; fd1 = pd1; fi1 = pi1; }
            else if (pd1 < fd2 || (pd1 == fd2 && pi1 < fi2)) { fd2 = pd1; fi2 = pi1; }
            if (pd2 < fd1 || (pd2 == fd1 && pi2 < fi1)) { fd2 = fd1; fi2 = fi1; fd1 = pd2; fi1 = pi2; }
            else if (pd2 < fd2 || (pd2 == fd2 && pi2 < fi2)) { fd2 = pd2; fi2 = pi2; }
        }
        int row = row0 + tid;
        idxOut[row] = fi1;
        flags[row] = (fd2 - fd1 < MARGIN) ? 1 : 0;
    }
}

// last-stage: folded refine of stage-2 flagged rows, then update:
// r = in - cb[idx]; qtot = z - r; SSE per block; counts.
__global__ __launch_bounds__(256) void update_kernel(
    const float* __restrict__ in, const float* __restrict__ z,
    float* __restrict__ qtotOut,
    const float* __restrict__ cbD, int* idxStage,
    const int* __restrict__ flags,
    int* __restrict__ counts, double* __restrict__ ssepart)
{
    __shared__ float4 rres[64];
    __shared__ double bd[256];
    __shared__ int    bidxS[256];
    __shared__ int    list[16];
    __shared__ int    nflag;
    __shared__ double wsum[4];
    const int tid = threadIdx.x;

    // ---- folded refine: this block's 16 rows ----
    if (tid == 0) nflag = 0;
    __syncthreads();
    if (tid < 16) {
        int row = (tid >> 2) * 8192 + blockIdx.x * 4 + (tid & 3);
        if (flags[row]) { int pos = atomicAdd(&nflag, 1); list[pos] = row; }
    }
    __syncthreads();
    const int nf = nflag;
    for (int f = 0; f < nf; ++f) {
        int row = list[f];
        if (tid < 64)
            rres[tid] = ((const float4*)(in + (size_t)row * D))[tid];
        __syncthreads();
        double best = 1e300; int bi = 0;
        for (int j = 0; j < 4; ++j) {
            int c = tid * 4 + j;
            const float4* cp = (const float4*)(cbD + (size_t)c * D);
            double s0 = 0.0, s1 = 0.0, s2 = 0.0, s3 = 0.0;
            for (int k = 0; k < 16; ++k) {
                float4 c0 = cp[k], c1 = cp[k + 16], c2 = cp[k + 32], c3 = cp[k + 48];
                float4 r0 = rres[k], r1 = rres[k + 16], r2 = rres[k + 32], r3 = rres[k + 48];
                double a;
                a = (double)r0.x - (double)c0.x; s0 = fma(a, a, s0);
                a = (double)r0.y - (double)c0.y; s0 = fma(a, a, s0);
                a = (double)r0.z - (double)c0.z; s0 = fma(a, a, s0);
                a = (double)r0.w - (double)c0.w; s0 = fma(a, a, s0);
                a = (double)r1.x - (double)c1.x; s1 = fma(a, a, s1);
                a = (double)r1.y - (double)c1.y; s1 = fma(a, a, s1);
                a = (double)r1.z - (double)c1.z; s1 = fma(a, a, s1);
                a = (double)r1.w - (double)c1.w; s1 = fma(a, a, s1);
                a = (double)r2.x - (double)c2.x; s2 = fma(a, a, s2);
                a = (double)r2.y - (double)c2.y; s2 = fma(a, a, s2);
                a = (double)r2.z - (double)c2.z; s2 = fma(a, a, s2);
                a = (double)r2.w - (double)c2.w; s2 = fma(a, a, s2);
                a = (double)r3.x - (double)c3.x; s3 = fma(a, a, s3);
                a = (double)r3.y - (double)c3.y; s3 = fma(a, a, s3);
                a = (double)r3.z - (double)c3.z; s3 = fma(a, a, s3);
                a = (double)r3.w - (double)c3.w; s3 = fma(a, a, s3);
            }
            double s = (s0 + s1) + (s2 + s3);
            if (s < best || (s == best && c < bi)) { best = s; bi = c; }
        }
        bd[tid] = best; bidxS[tid] = bi;
        __syncthreads();
        for (int off = 128; off > 0; off >>= 1) {
            if (tid < off) {
                if (bd[tid + off] < bd[tid] ||
                    (bd[tid + off] == bd[tid] && bidxS[tid + off] < bidxS[tid])) {
                    bd[tid] = bd[tid + off]; bidxS[tid] = bidxS[tid + off];
                }
            }
            __syncthreads();
        }
        if (tid == 0) idxStage[row] = bidxS[0];
        __syncthreads();
    }
    __syncthreads();   // refined idx visible block-wide

    // ---- streaming update ----
    double s = 0.0;
    const int base = blockIdx.x * 256 + tid;
    #pragma unroll
    for (int it = 0; it < 4; ++it) {
        int t = base + it * 524288;
        int row = t >> 6;
        int c4  = (t & 63) << 2;
        int idx = idxStage[row];
        size_t off = (size_t)row * D + c4;
        float4 iv = *(const float4*)(in + off);
        float4 cv = *(const float4*)(cbD + (size_t)idx * D + c4);
        float4 r;
        r.x = iv.x - cv.x; r.y = iv.y - cv.y;
        r.z = iv.z - cv.z; r.w = iv.w - cv.w;
        float4 zv = *(const float4*)(z + off);
        float4 q;
        q.x = zv.x - r.x; q.y = zv.y - r.y;
        q.z = zv.z - r.z; q.w = zv.w - r.w;
        *(float4*)(qtotOut + off) = q;
        s = fma((double)r.x, (double)r.x, s);
        s = fma((double)r.y, (double)r.y, s);
        s = fma((double)r.z, (double)r.z, s);
        s = fma((double)r.w, (double)r.w, s);
        if ((t & 63) == 0) atomicAdd(counts + idx, 1);
    }
    for (int o = 32; o > 0; o >>= 1) s += __shfl_down(s, o, 64);
    int lane = tid & 63, wv = tid >> 6;
    if (lane == 0) wsum[wv] = s;
    __syncthreads();
    if (tid == 0)
        ssepart[blockIdx.x] = wsum[0] + wsum[1] + wsum[2] + wsum[3];
}

// compose + perplexity + loss
__global__ void final_kernel(const int* __restrict__ idxAll, const int* __restrict__ counts,
                             const double* __restrict__ ssepart,
                             float* __restrict__ loss, float* __restrict__ comp,
                             float* __restrict__ perps)
{
    __shared__ double red[16];
    __shared__ double lossAcc;
    const int tid = threadIdx.x;   // 1024 threads
    for (int n = tid; n < N_ROWS; n += 1024) {
        int v = idxAll[n] + (idxAll[N_ROWS + n] << 10) + (idxAll[2 * N_ROWS + n] << 20);
        comp[n] = (float)v;
    }
    if (tid == 0) lossAcc = 0.0;
    __syncthreads();
    for (int d = 0; d < DEPTH; ++d) {
        double p = (double)counts[d * K + tid] / 32768.0;
        double s = p * log(p + 1e-10);
        double q = ssepart[d * 2048 + tid] + ssepart[d * 2048 + 1024 + tid];
        for (int o = 32; o > 0; o >>= 1) {
            s += __shfl_down(s, o, 64);
            q += __shfl_down(q, o, 64);
        }
        if ((tid & 63) == 0) red[tid >> 6] = s;
        __syncthreads();
        if (tid == 0) {
            double tot = 0.0;
            for (int i = 0; i < 16; ++i) tot += red[i];
            perps[d] = (float)exp(-tot);
        }
        __syncthreads();
        if ((tid & 63) == 0) red[tid >> 6] = q;
        __syncthreads();
        if (tid == 0) {
            double tq = 0.0;
            for (int i = 0; i < 16; ++i) tq += red[i];
            lossAcc += tq;
        }
        __syncthreads();
    }
    if (tid == 0)
        loss[0] = (float)(1.25 * lossAcc / 8388608.0);
}

extern "C" void kernel_launch(void* const* d_in, const int* in_sizes, int n_in,
                              void* d_out, int out_size, void* d_ws, size_t ws_size,
                              hipStream_t stream)
{
    const float* z   = (const float*)d_in[0];
    const float* cbs = (const float*)d_in[1];
    float* out = (float*)d_out;
    char*  ws  = (char*)d_ws;

    int*            idxAll   = (int*)ws;
    int*            counts   = (int*)(ws + 393216);
    int*            flags    = (int*)(ws + 405504);
    double*         ssepart  = (double*)(ws + 536576);
    float*          e2f      = (float*)(ws + 585728);
    unsigned short* cbp      = (unsigned short*)(ws + 598080);
    float*          res      = (float*)(ws + 3743808);

    float* qtot  = out;                       // 8388608 elems
    float* loss  = out + 8388608;             // 1
    float* comp  = out + 8388609;             // 32768
    float* perps = out + 8388609 + 32768;     // 3

    prep_kernel<<<385, 256, 0, stream>>>(cbs, cbp, e2f, counts);

    for (int d = 0; d < DEPTH; ++d) {
        const float* in = (d <= 1) ? z : res;
        int*         pIdx = (d == 0) ? idxAll : idxAll + (d - 1) * N_ROWS;
        const float* pCb  = (d == 0) ? cbs : cbs + (size_t)(d - 1) * K * D;
        mfma_argmin_kernel<<<256, 512, 0, stream>>>(
            cbp + (size_t)d * K * 512, in, e2f + d * K,
            idxAll + d * N_ROWS, flags,
            pIdx, pCb, res, ssepart + (size_t)(d - 1) * 2048,
            counts + (d - 1) * K, (d == 0) ? 1 : 0);
    }

    update_kernel<<<2048, 256, 0, stream>>>(
        res, z, qtot, cbs + (size_t)2 * K * D, idxAll + 2 * N_ROWS, flags,
        counts + 2 * K, ssepart + 2 * 2048);

    final_kernel<<<1, 1024, 0, stream>>>(idxAll, counts, ssepart, loss, comp, perps);
}